// Round 16
// baseline (194.050 us; speedup 1.0000x reference)
//
#include <hip/hip_runtime.h>
#include <cstdint>

#define HW 3136
#define WID 56
#define NBLK 1792   // 32 frame-pairs * 56 rows
#define RSTR 14336  // u32 elements per transposed row-block: 256 ch * 56 col

typedef float f4v __attribute__((ext_vector_type(4)));

__device__ __forceinline__ int clampi(int v, int lo, int hi) {
    return v < lo ? lo : (v > hi ? hi : v);
}
__device__ __forceinline__ uint32_t rne16(float f) {   // fp32 -> bf16 (RNE)
    uint32_t b = __float_as_uint(f);
    return (b + 0x7fffu + ((b >> 16) & 1u)) >> 16;
}
__device__ __forceinline__ float blo(uint32_t u) { return __uint_as_float(u << 16); }
__device__ __forceinline__ float bhi(uint32_t u) { return __uint_as_float(u & 0xffff0000u); }
__device__ __forceinline__ uint32_t bpermu(int a4, uint32_t v) {
    return (uint32_t)__builtin_amdgcn_ds_bpermute(a4, (int)v);
}
__device__ __forceinline__ float bperm(int a4, float v) {
    return __int_as_float(__builtin_amdgcn_ds_bpermute(a4, __float_as_int(v)));
}
__device__ __forceinline__ void fma2(float2& a, const float2& u, const float2& w) {
    a.x += u.x * w.x; a.y += u.y * w.y;
}

// ---------- pass A: stream x (NT loads) -> TRANSPOSED packed bf16 buffer
// xb[pair][row][ch][col], u32 = bf16(even) | bf16(odd)<<16. (unchanged, R15)
__global__ __launch_bounds__(256) void tf_pack_t(const float* __restrict__ x,
                                                 uint32_t* __restrict__ xb)
{
    const unsigned total4 = 8192u * 784u;
    unsigned i = blockIdx.x * 256u + threadIdx.x;
    const unsigned stride = gridDim.x * 256u;
    uint4* xb4 = (uint4*)xb;
    for (; i < total4; i += stride) {
        const unsigned p4 = i / 784u;
        const unsigned i4 = i - p4 * 784u;
        const unsigned pair = p4 >> 8;
        const unsigned ch = p4 & 255u;
        const unsigned row = i4 / 14u;
        const unsigned c4 = i4 - row * 14u;
        const size_t eoff = ((size_t)pair * 512 + ch) * HW + i4 * 4;
        const f4v e = __builtin_nontemporal_load((const f4v*)(x + eoff));
        const f4v o = __builtin_nontemporal_load((const f4v*)(x + eoff + (size_t)256 * HW));
        uint4 u;
        u.x = (rne16(o.x) << 16) | rne16(e.x);
        u.y = (rne16(o.y) << 16) | rne16(e.y);
        u.z = (rne16(o.z) << 16) | rne16(e.z);
        u.w = (rne16(o.w) << 16) | rne16(e.w);
        xb4[(((size_t)pair * 56 + row) * 256 + ch) * 14 + c4] = u;
    }
}

// ---------- pass B: fused corr -> W -> gather; float2-of-u32 taps (2 px,
// both frames per load). R12's lane structure + 2-slot reduce + R13 prefetch
// on the transposed layout. 192 uint2 loads + 384 bperm per thread (half of
// R15). LDS = CP 4032 + CR 16128 = 20160 B.
__global__ __launch_bounds__(256, 2) void tf_fused_t2(
    const uint32_t* __restrict__ xb, const float* __restrict__ wconv,
    const float* __restrict__ bconv, float* __restrict__ out)
{
    __shared__ float2 CP[2 * 9 * 28];   // 4032 B
    __shared__ float  CR[72 * 56];      // 16128 B

    const int d = blockIdx.x;
    const int logical = (d & 7) * 224 + (d >> 3);   // XCD-contiguous rows
    const int n  = logical / 56;
    const int r0 = logical % 56;
    const int t = threadIdx.x;
    const int wv = t >> 6;
    const int l = t & 63;
    const int sub = l >> 5;             // 0..1
    const int s8 = wv * 2 + sub;        // channel slice 0..7
    const int qd0 = l & 31;
    const bool act = qd0 < 28;
    const int qd = act ? qd0 : 27;

    const uint32_t* xq = xb + (size_t)n * 56 * RSTR;

    // neighbor-lane bperm addresses; image edge via le/re selects
    const int am = ((qd0 == 0) ? l : (l - 1)) * 4;
    const int ap = ((qd0 >= 27) ? l : (l + 1)) * 4;
    const bool le = (qd0 == 0);    // px0 left tap = own .x
    const bool re = (qd0 >= 27);   // px55 right tap = own .y

    const int Rm = clampi(r0 - 1, 0, 55) * RSTR;
    const int Rc = r0 * RSTR;
    const int Rp = clampi(r0 + 1, 0, 55) * RSTR;
    const int co0 = qd * 2;             // column offset of this thread's px pair

    // ================= phase 1: corr -> CR =================
    for (int g = 0; g < 8; ++g) {
        float2 crg[9];
        #pragma unroll
        for (int i = 0; i < 9; ++i) crg[i] = make_float2(0.f, 0.f);

        #pragma unroll
        for (int c = 0; c < 4; ++c) {
            const int co = (g * 32 + 4 * s8 + c) * 56 + co0;
            const uint2 U0 = *(const uint2*)(xq + Rm + co);
            const uint2 U1 = *(const uint2*)(xq + Rc + co);
            const uint2 U2 = *(const uint2*)(xq + Rp + co);
            const float e0 = blo(U1.x), e1 = blo(U1.y);   // even frame, center px pair
            #pragma unroll
            for (int r = 0; r < 3; ++r) {
                const uint2 U = (r == 0) ? U0 : ((r == 1) ? U1 : U2);
                uint32_t lw = bpermu(am, U.y); if (le) lw = U.x;
                uint32_t rw = bpermu(ap, U.x); if (re) rw = U.y;
                crg[r * 3 + 0].x += e0 * bhi(lw);
                crg[r * 3 + 0].y += e1 * bhi(U.x);
                crg[r * 3 + 1].x += e0 * bhi(U.x);
                crg[r * 3 + 1].y += e1 * bhi(U.y);
                crg[r * 3 + 2].x += e0 * bhi(U.y);
                crg[r * 3 + 2].y += e1 * bhi(rw);
            }
        }

        // fold the wave's two sub-slices (lanes l and l^32 share qd)
        #pragma unroll
        for (int ij = 0; ij < 9; ++ij) {
            crg[ij].x += __shfl_xor(crg[ij].x, 32);
            crg[ij].y += __shfl_xor(crg[ij].y, 32);
        }
        // 2-slot reduce (R12): waves 0,1 publish; 2,3 accumulate; wave 0 -> CR
        if (wv < 2 && sub == 0 && act) {
            #pragma unroll
            for (int ij = 0; ij < 9; ++ij) CP[(wv * 9 + ij) * 28 + qd] = crg[ij];
        }
        __syncthreads();
        if (wv >= 2 && sub == 0 && act) {
            const int sl = wv - 2;
            #pragma unroll
            for (int ij = 0; ij < 9; ++ij) {
                float2 v = CP[(sl * 9 + ij) * 28 + qd];
                v.x += crg[ij].x; v.y += crg[ij].y;
                CP[(sl * 9 + ij) * 28 + qd] = v;
            }
        }
        __syncthreads();
        if (wv == 0 && sub == 0 && act) {
            #pragma unroll
            for (int ij = 0; ij < 9; ++ij) {
                const float2 v0 = CP[(0 * 9 + ij) * 28 + qd];
                const float2 v1 = CP[(1 * 9 + ij) * 28 + qd];
                float2 v;
                v.x = v0.x + v1.x; v.y = v0.y + v1.y;
                *(float2*)(CR + (ij * 8 + g) * 56 + qd * 2) = v;
            }
        }
        __syncthreads();
    }

    // ---- hoist: 18 float2 weights (gl = s8, this thread's 2 px) ----
    float2 We[9], Wo[9];
    #pragma unroll
    for (int ij = 0; ij < 9; ++ij) {
        const int fe = ij * 16 + 2 * s8;     // even-frame weight; fe+1 = odd
        const int a = fe / 18;
        const float be = bconv[fe], bo = bconv[fe + 1];
        float2 we = make_float2(be, be);
        float2 wo = make_float2(bo, bo);
        #pragma unroll
        for (int b = 0; b < 9; ++b) {
            const float2 c2 = *(const float2*)(CR + (a * 9 + b) * 56 + qd * 2);
            const float wce = wconv[fe * 9 + b];
            const float wco = wconv[fe * 9 + 9 + b];
            we.x += c2.x * wce; we.y += c2.y * wce;
            wo.x += c2.x * wco; wo.y += c2.y * wco;
        }
        We[ij] = we; Wo[ij] = wo;
    }

    // ========== phase 3: barrier-free gather, depth-1 prefetch ==========
    float* ob = out + (size_t)n * 256 * HW + r0 * WID + co0;

    uint2 C0 = *(const uint2*)(xq + Rm + s8 * 56 + co0);
    uint2 C1 = *(const uint2*)(xq + Rc + s8 * 56 + co0);
    uint2 C2 = *(const uint2*)(xq + Rp + s8 * 56 + co0);

    #pragma unroll 2
    for (int k = 0; k < 32; ++k) {
        const int kn = (k < 31) ? k + 1 : 31;
        const int con = (kn * 8 + s8) * 56 + co0;
        const uint2 N0 = *(const uint2*)(xq + Rm + con);
        const uint2 N1 = *(const uint2*)(xq + Rc + con);
        const uint2 N2 = *(const uint2*)(xq + Rp + con);

        float2 acc = make_float2(0.f, 0.f);
        #pragma unroll
        for (int r = 0; r < 3; ++r) {
            const uint2 U = (r == 0) ? C0 : ((r == 1) ? C1 : C2);
            uint32_t lw = bpermu(am, U.y); if (le) lw = U.x;
            uint32_t rw = bpermu(ap, U.x); if (re) rw = U.y;
            acc.x += blo(lw)  * We[r * 3 + 0].x + bhi(lw)  * Wo[r * 3 + 0].x;
            acc.y += blo(U.x) * We[r * 3 + 0].y + bhi(U.x) * Wo[r * 3 + 0].y;
            acc.x += blo(U.x) * We[r * 3 + 1].x + bhi(U.x) * Wo[r * 3 + 1].x;
            acc.y += blo(U.y) * We[r * 3 + 1].y + bhi(U.y) * Wo[r * 3 + 1].y;
            acc.x += blo(U.y) * We[r * 3 + 2].x + bhi(U.y) * Wo[r * 3 + 2].x;
            acc.y += blo(rw)  * We[r * 3 + 2].y + bhi(rw)  * Wo[r * 3 + 2].y;
        }
        if (act) *(float2*)(ob + (size_t)(k * 8 + s8) * HW) = acc;

        C0 = N0; C1 = N1; C2 = N2;
    }
}

// ---------- fallback (ws too small): R13 fp32 kernel ----------
__global__ __launch_bounds__(256, 2) void tf_fused_f32(
    const float* __restrict__ x, const float* __restrict__ wconv,
    const float* __restrict__ bconv, float* __restrict__ out)
{
    __shared__ float2 CP[2 * 9 * 28];
    __shared__ float  CR[72 * 56];

    const int d = blockIdx.x;
    const int logical = (d & 7) * 224 + (d >> 3);
    const int n  = logical / 56;
    const int r0 = logical % 56;
    const int t = threadIdx.x;
    const int wv = t >> 6;
    const int l = t & 63;
    const int sub = l >> 5;
    const int s8 = wv * 2 + sub;
    const int qd0 = l & 31;
    const bool act = qd0 < 28;
    const int qd = act ? qd0 : 27;

    const float* xe = x + (size_t)(2 * n) * 256 * HW;
    const float* xo = xe + (size_t)256 * HW;

    const int am = ((qd0 == 0) ? l : (l - 1)) * 4;
    const int ap = ((qd0 >= 27) ? l : (l + 1)) * 4;
    const bool le = (qd0 == 0);
    const bool re = (qd0 >= 27);

    int rb[3];
    #pragma unroll
    for (int di = 0; di < 3; ++di) rb[di] = clampi(r0 + di - 1, 0, 55) * WID + qd * 2;
    const int rc = r0 * WID + qd * 2;

#define MKTAPS2(v, Tm, Tp)                                  \
    {                                                       \
        const float lwp = bperm(am, (v).y);                 \
        const float rwp = bperm(ap, (v).x);                 \
        Tm = make_float2(le ? (v).x : lwp, (v).x);          \
        Tp = make_float2((v).y, re ? (v).y : rwp);          \
    }

    for (int g = 0; g < 8; ++g) {
        const int ch0 = g * 32 + 4 * s8;
        const float* pe = xe + (size_t)ch0 * HW;
        const float* po = xo + (size_t)ch0 * HW;
        float2 crg[9];
        #pragma unroll
        for (int i = 0; i < 9; ++i) crg[i] = make_float2(0.f, 0.f);
        #pragma unroll
        for (int c = 0; c < 4; ++c) {
            const float2 E = *(const float2*)(pe + (size_t)c * HW + rc);
            #pragma unroll
            for (int di = 0; di < 3; ++di) {
                const float2 O = *(const float2*)(po + (size_t)c * HW + rb[di]);
                float2 Tm, Tp;
                MKTAPS2(O, Tm, Tp)
                fma2(crg[di * 3 + 0], E, Tm);
                fma2(crg[di * 3 + 1], E, O);
                fma2(crg[di * 3 + 2], E, Tp);
            }
        }
        #pragma unroll
        for (int ij = 0; ij < 9; ++ij) {
            crg[ij].x += __shfl_xor(crg[ij].x, 32);
            crg[ij].y += __shfl_xor(crg[ij].y, 32);
        }
        if (wv < 2 && sub == 0 && act) {
            #pragma unroll
            for (int ij = 0; ij < 9; ++ij) CP[(wv * 9 + ij) * 28 + qd] = crg[ij];
        }
        __syncthreads();
        if (wv >= 2 && sub == 0 && act) {
            const int sl = wv - 2;
            #pragma unroll
            for (int ij = 0; ij < 9; ++ij) {
                float2 v = CP[(sl * 9 + ij) * 28 + qd];
                v.x += crg[ij].x; v.y += crg[ij].y;
                CP[(sl * 9 + ij) * 28 + qd] = v;
            }
        }
        __syncthreads();
        if (wv == 0 && sub == 0 && act) {
            #pragma unroll
            for (int ij = 0; ij < 9; ++ij) {
                const float2 v0 = CP[(0 * 9 + ij) * 28 + qd];
                const float2 v1 = CP[(1 * 9 + ij) * 28 + qd];
                float2 v;
                v.x = v0.x + v1.x; v.y = v0.y + v1.y;
                *(float2*)(CR + (ij * 8 + g) * 56 + qd * 2) = v;
            }
        }
        __syncthreads();
    }

    float2 We[9], Wo[9];
    #pragma unroll
    for (int ij = 0; ij < 9; ++ij) {
        const int fe = ij * 16 + 2 * s8;
        const int a = fe / 18;
        const float be = bconv[fe], bo = bconv[fe + 1];
        float2 we = make_float2(be, be);
        float2 wo = make_float2(bo, bo);
        #pragma unroll
        for (int b = 0; b < 9; ++b) {
            const float2 c2 = *(const float2*)(CR + (a * 9 + b) * 56 + qd * 2);
            const float wce = wconv[fe * 9 + b];
            const float wco = wconv[fe * 9 + 9 + b];
            we.x += c2.x * wce; we.y += c2.y * wce;
            wo.x += c2.x * wco; wo.y += c2.y * wco;
        }
        We[ij] = we; Wo[ij] = wo;
    }

    float* ob = out + (size_t)n * 256 * HW + r0 * WID + qd * 2;
    #pragma unroll 2
    for (int k = 0; k < 32; ++k) {
        const int ch = k * 8 + s8;
        const float* pe = xe + (size_t)ch * HW;
        const float* po = xo + (size_t)ch * HW;
        float2 acc = make_float2(0.f, 0.f);
        #pragma unroll
        for (int di = 0; di < 3; ++di) {
            const float2 Ev = *(const float2*)(pe + rb[di]);
            const float2 Ov = *(const float2*)(po + rb[di]);
            float2 TEm, TEp, TOm, TOp;
            MKTAPS2(Ev, TEm, TEp)
            MKTAPS2(Ov, TOm, TOp)
            fma2(acc, TEm, We[di * 3 + 0]); fma2(acc, TOm, Wo[di * 3 + 0]);
            fma2(acc, Ev,  We[di * 3 + 1]); fma2(acc, Ov,  Wo[di * 3 + 1]);
            fma2(acc, TEp, We[di * 3 + 2]); fma2(acc, TOp, Wo[di * 3 + 2]);
        }
        if (act) *(float2*)(ob + (size_t)ch * HW) = acc;
    }
#undef MKTAPS2
}

// partial BN stats
__global__ void tf_stats_part(const float* __restrict__ out,
                              float* __restrict__ ps, float* __restrict__ pq)
{
    const int ch = blockIdx.x >> 3;
    const int sl = blockIdx.x & 7;
    const int t = threadIdx.x;

    float s = 0.f, q = 0.f;
    #pragma unroll
    for (int k = 0; k < 4; ++k) {
        const float4* p = (const float4*)(out + ((size_t)(4 * sl + k) * 256 + ch) * HW);
        for (int i = t; i < 784; i += 256) {
            const float4 v = p[i];
            s += v.x + v.y + v.z + v.w;
            q += v.x * v.x + v.y * v.y + v.z * v.z + v.w * v.w;
        }
    }
    #pragma unroll
    for (int o = 32; o >= 1; o >>= 1) {
        s += __shfl_xor(s, o);
        q += __shfl_xor(q, o);
    }
    __shared__ float rs[4], rq[4];
    if ((t & 63) == 0) { rs[t >> 6] = s; rq[t >> 6] = q; }
    __syncthreads();
    if (t == 0) {
        ps[blockIdx.x] = rs[0] + rs[1] + rs[2] + rs[3];
        pq[blockIdx.x] = rq[0] + rq[1] + rq[2] + rq[3];
    }
}

__global__ void tf_stats_fin(const float* __restrict__ ps, const float* __restrict__ pq,
                             const float* __restrict__ gamma, const float* __restrict__ beta,
                             float* __restrict__ AB)
{
    const int ch = threadIdx.x;
    float s = 0.f, q = 0.f;
    #pragma unroll
    for (int sl = 0; sl < 8; ++sl) {
        s += ps[ch * 8 + sl];
        q += pq[ch * 8 + sl];
    }
    const float inv = 1.f / 100352.f;
    const float mean = s * inv;
    const float var = q * inv - mean * mean;
    const float rstd = rsqrtf(var + 1e-5f);
    const float A = gamma[ch] * rstd;
    AB[ch] = A;
    AB[256 + ch] = beta[ch] - mean * A;
}

__global__ void tf_norm(float* __restrict__ out, const float* __restrict__ AB)
{
    const unsigned total4 = 32u * 256u * 784u;
    unsigned i = blockIdx.x * 256u + threadIdx.x;
    const unsigned stride = gridDim.x * 256u;
    float4* o4 = (float4*)out;
    for (; i < total4; i += stride) {
        const unsigned ch = (i / 784u) & 255u;
        const float A = AB[ch], B = AB[256 + ch];
        float4 v = o4[i];
        v.x = v.x * A + B;
        v.y = v.y * A + B;
        v.z = v.z * A + B;
        v.w = v.w * A + B;
        o4[i] = v;
    }
}

extern "C" void kernel_launch(void* const* d_in, const int* in_sizes, int n_in,
                              void* d_out, int out_size, void* d_ws, size_t ws_size,
                              hipStream_t stream) {
    const float* x     = (const float*)d_in[0];
    const float* wconv = (const float*)d_in[1];
    const float* bconv = (const float*)d_in[2];
    const float* gamma = (const float*)d_in[3];
    const float* beta  = (const float*)d_in[4];
    float* out = (float*)d_out;

    float* ps = (float*)d_ws;                    // [2048]
    float* pq = ps + 2048;                       // [2048]
    float* AB = pq + 2048;                       // [512]
    uint32_t* xbuf = (uint32_t*)((uint8_t*)d_ws + 32768);
    const size_t need = 32768 + (size_t)32 * 56 * RSTR * 4;   // ~102.8 MB

    if (ws_size >= need) {
        tf_pack_t<<<4096, 256, 0, stream>>>(x, xbuf);
        tf_fused_t2<<<NBLK, 256, 0, stream>>>(xbuf, wconv, bconv, out);
    } else {
        tf_fused_f32<<<NBLK, 256, 0, stream>>>(x, wconv, bconv, out);
    }
    tf_stats_part<<<2048, 256, 0, stream>>>(out, ps, pq);
    tf_stats_fin<<<1, 256, 0, stream>>>(ps, pq, gamma, beta, AB);
    tf_norm<<<2048, 256, 0, stream>>>(out, AB);
}

// Round 18
// 178.699 us; speedup vs baseline: 1.0859x; 1.0859x over previous
//
#include <hip/hip_runtime.h>
#include <cstdint>

#define HW 3136
#define WID 56
#define NBLK 1792   // 32 frame-pairs * 56 rows

typedef float f2v __attribute__((ext_vector_type(2)));
typedef float f4v __attribute__((ext_vector_type(4)));

__device__ __forceinline__ int clampi(int v, int lo, int hi) {
    return v < lo ? lo : (v > hi ? hi : v);
}

__device__ __forceinline__ float bperm(int a4, float v) {
    return __int_as_float(__builtin_amdgcn_ds_bpermute(a4, __float_as_int(v)));
}

__device__ __forceinline__ void fma2(float2& a, const float2& u, const float2& w) {
    a.x += u.x * w.x; a.y += u.y * w.y;
}

__device__ __forceinline__ void nt_store2(float* p, float2 v) {
    f2v t; t.x = v.x; t.y = v.y;
    __builtin_nontemporal_store(t, (f2v*)p);
}

// R13 (best: 164us fused / 179 total) + ONE change: non-temporal output
// stores. Theory: the 32 scattered 224-B partial-line stores per thread are
// write-allocate RMW misses sharing the vmcnt counter with the prefetch
// loads -- every s_waitcnt before a tap-use drains them, putting ~700-cyc
// store latency on the critical path 32x per thread. NT stores skip the
// allocate/RMW and retire faster.
// Block = 1 output row (56 px); 256 thr = 4 waves; s8 = wv*2+(l>>5) channel
// slice; qd = l&31 (28 float2 quads). LDS = CP 4032 + CR 16128 = 20160 B ->
// 8 blocks/CU. (256,2): the only non-spilling launch_bounds. Depth-1
// prefetch in both phases.
__global__ __launch_bounds__(256, 2) void tf_fused(
    const float* __restrict__ x, const float* __restrict__ wconv,
    const float* __restrict__ bconv, float* __restrict__ out)
{
    __shared__ float2 CP[2 * 9 * 28];   // 4032 B
    __shared__ float  CR[72 * 56];      // 16128 B

    const int d = blockIdx.x;
    const int logical = (d & 7) * 224 + (d >> 3);   // XCD-contiguous rows
    const int n  = logical / 56;
    const int r0 = logical % 56;
    const int t = threadIdx.x;
    const int wv = t >> 6;
    const int l = t & 63;
    const int sub = l >> 5;             // 0..1
    const int s8 = wv * 2 + sub;        // channel slice 0..7
    const int qd0 = l & 31;
    const bool act = qd0 < 28;
    const int qd = act ? qd0 : 27;

    const float* xe = x + (size_t)(2 * n) * 256 * HW;
    const float* xo = xe + (size_t)256 * HW;

    // quad-edge bperm addresses (neighbor lane), image-edge via le/re selects
    const int am = ((qd0 == 0) ? l : (l - 1)) * 4;
    const int ap = ((qd0 >= 27) ? l : (l + 1)) * 4;
    const bool le = (qd0 == 0);    // px 0: left tap = own .x
    const bool re = (qd0 >= 27);   // px 55: right tap = own .y

    int rb[3];   // row bases (edge-clamped); literal-indexed only
    #pragma unroll
    for (int di = 0; di < 3; ++di) rb[di] = clampi(r0 + di - 1, 0, 55) * WID + qd * 2;
    const int rc = r0 * WID + qd * 2;

    // shifted tap pair from own float2: 2 bperm + 2 selects
#define MKTAPS2(v, Tm, Tp)                                  \
    {                                                       \
        const float lwp = bperm(am, (v).y);                 \
        const float rwp = bperm(ap, (v).x);                 \
        Tm = make_float2(le ? (v).x : lwp, (v).x);          \
        Tp = make_float2((v).y, re ? (v).y : rwp);          \
    }

    // chunk m in 0..31: channel = (m>>2)*32 + 4*s8 + (m&3)
    auto ldE = [&](int m) -> float2 {
        const float* p = xe + (size_t)((m >> 2) * 32 + 4 * s8 + (m & 3)) * HW;
        return *(const float2*)(p + rc);
    };
    auto ldO = [&](int m, int di) -> float2 {
        const float* p = xo + (size_t)((m >> 2) * 32 + 4 * s8 + (m & 3)) * HW;
        return *(const float2*)(p + rb[di]);
    };

    // ================= phase 1: corr -> CR (prefetch pipelined) =================
    float2 Ec = ldE(0);
    float2 Oc0 = ldO(0, 0), Oc1 = ldO(0, 1), Oc2 = ldO(0, 2);

    for (int g = 0; g < 8; ++g) {
        float2 crg[9];
        #pragma unroll
        for (int i = 0; i < 9; ++i) crg[i] = make_float2(0.f, 0.f);

        #pragma unroll
        for (int c = 0; c < 4; ++c) {
            const int m = g * 4 + c;
            const int mn = (m < 31) ? m + 1 : 31;   // next chunk (g+1 flies over barriers)
            const float2 En  = ldE(mn);
            const float2 On0 = ldO(mn, 0);
            const float2 On1 = ldO(mn, 1);
            const float2 On2 = ldO(mn, 2);

            float2 Tm, Tp;
            MKTAPS2(Oc0, Tm, Tp)
            fma2(crg[0], Ec, Tm); fma2(crg[1], Ec, Oc0); fma2(crg[2], Ec, Tp);
            MKTAPS2(Oc1, Tm, Tp)
            fma2(crg[3], Ec, Tm); fma2(crg[4], Ec, Oc1); fma2(crg[5], Ec, Tp);
            MKTAPS2(Oc2, Tm, Tp)
            fma2(crg[6], Ec, Tm); fma2(crg[7], Ec, Oc2); fma2(crg[8], Ec, Tp);

            Ec = En; Oc0 = On0; Oc1 = On1; Oc2 = On2;
        }

        // fold the wave's two sub-slices (lanes l and l^32 share qd)
        #pragma unroll
        for (int ij = 0; ij < 9; ++ij) {
            crg[ij].x += __shfl_xor(crg[ij].x, 32);
            crg[ij].y += __shfl_xor(crg[ij].y, 32);
        }

        // round A: waves 0,1 publish into slot 0/1
        if (wv < 2 && sub == 0 && act) {
            #pragma unroll
            for (int ij = 0; ij < 9; ++ij)
                CP[(wv * 9 + ij) * 28 + qd] = crg[ij];
        }
        __syncthreads();
        // round B: waves 2,3 accumulate into the slots
        if (wv >= 2 && sub == 0 && act) {
            const int sl = wv - 2;
            #pragma unroll
            for (int ij = 0; ij < 9; ++ij) {
                float2 v = CP[(sl * 9 + ij) * 28 + qd];
                v.x += crg[ij].x; v.y += crg[ij].y;
                CP[(sl * 9 + ij) * 28 + qd] = v;
            }
        }
        __syncthreads();
        // round C: wave 0 sums the two slots -> CR rows for this g
        if (wv == 0 && sub == 0 && act) {
            #pragma unroll
            for (int ij = 0; ij < 9; ++ij) {
                const float2 v0 = CP[(0 * 9 + ij) * 28 + qd];
                const float2 v1 = CP[(1 * 9 + ij) * 28 + qd];
                float2 v;
                v.x = v0.x + v1.x;
                v.y = v0.y + v1.y;
                *(float2*)(CR + (ij * 8 + g) * 56 + qd * 2) = v;
            }
        }
        __syncthreads();   // slots reusable next g; CR row visible
    }

    // ---- hoist: 18 float2 weights (this thread's gl = s8, at its 2 px) ----
    float2 We[9], Wo[9];
    #pragma unroll
    for (int ij = 0; ij < 9; ++ij) {
        const int fe = ij * 16 + 2 * s8;     // even-frame weight; fe+1 = odd
        const int a = fe / 18;               // (fe+1)/18 == a (fe even)
        const float be = bconv[fe], bo = bconv[fe + 1];
        float2 we = make_float2(be, be);
        float2 wo = make_float2(bo, bo);
        #pragma unroll
        for (int b = 0; b < 9; ++b) {
            const float2 c2 = *(const float2*)(CR + (a * 9 + b) * 56 + qd * 2);
            const float wce = wconv[fe * 9 + b];
            const float wco = wconv[fe * 9 + 9 + b];
            we.x += c2.x * wce; we.y += c2.y * wce;
            wo.x += c2.x * wco; wo.y += c2.y * wco;
        }
        We[ij] = we; Wo[ij] = wo;
    }

    // ============ phase 3: weighted gather (prefetch + NT stores) ============
    float* ob = out + (size_t)n * 256 * HW + r0 * WID + qd * 2;

    auto ldP = [&](const float* base, int k, int di) -> float2 {
        return *(const float2*)(base + (size_t)(k * 8 + s8) * HW + rb[di]);
    };

    float2 Eb0 = ldP(xe, 0, 0), Eb1 = ldP(xe, 0, 1), Eb2 = ldP(xe, 0, 2);
    float2 Ob0 = ldP(xo, 0, 0), Ob1 = ldP(xo, 0, 1), Ob2 = ldP(xo, 0, 2);

    #pragma unroll 2
    for (int k = 0; k < 32; ++k) {
        const int kn = (k < 31) ? k + 1 : 31;
        const float2 En0 = ldP(xe, kn, 0), En1 = ldP(xe, kn, 1), En2 = ldP(xe, kn, 2);
        const float2 On0 = ldP(xo, kn, 0), On1 = ldP(xo, kn, 1), On2 = ldP(xo, kn, 2);

        float2 acc = make_float2(0.f, 0.f);
        float2 Tm, Tp;
        MKTAPS2(Eb0, Tm, Tp)
        fma2(acc, Tm, We[0]); fma2(acc, Eb0, We[1]); fma2(acc, Tp, We[2]);
        MKTAPS2(Ob0, Tm, Tp)
        fma2(acc, Tm, Wo[0]); fma2(acc, Ob0, Wo[1]); fma2(acc, Tp, Wo[2]);
        MKTAPS2(Eb1, Tm, Tp)
        fma2(acc, Tm, We[3]); fma2(acc, Eb1, We[4]); fma2(acc, Tp, We[5]);
        MKTAPS2(Ob1, Tm, Tp)
        fma2(acc, Tm, Wo[3]); fma2(acc, Ob1, Wo[4]); fma2(acc, Tp, Wo[5]);
        MKTAPS2(Eb2, Tm, Tp)
        fma2(acc, Tm, We[6]); fma2(acc, Eb2, We[7]); fma2(acc, Tp, We[8]);
        MKTAPS2(Ob2, Tm, Tp)
        fma2(acc, Tm, Wo[6]); fma2(acc, Ob2, Wo[7]); fma2(acc, Tp, Wo[8]);

        if (act)
            nt_store2(ob + (size_t)(k * 8 + s8) * HW, acc);

        Eb0 = En0; Eb1 = En1; Eb2 = En2;
        Ob0 = On0; Ob1 = On1; Ob2 = On2;
    }
#undef MKTAPS2
}

// partial BN stats: block bid -> channel bid>>3, frame-pair slice bid&7 (4 pairs)
__global__ void tf_stats_part(const float* __restrict__ out,
                              float* __restrict__ ps, float* __restrict__ pq)
{
    const int ch = blockIdx.x >> 3;
    const int sl = blockIdx.x & 7;
    const int t = threadIdx.x;

    float s = 0.f, q = 0.f;
    #pragma unroll
    for (int k = 0; k < 4; ++k) {
        const float4* p = (const float4*)(out + ((size_t)(4 * sl + k) * 256 + ch) * HW);
        for (int i = t; i < 784; i += 256) {
            const float4 v = p[i];
            s += v.x + v.y + v.z + v.w;
            q += v.x * v.x + v.y * v.y + v.z * v.z + v.w * v.w;
        }
    }
    #pragma unroll
    for (int o = 32; o >= 1; o >>= 1) {
        s += __shfl_xor(s, o);
        q += __shfl_xor(q, o);
    }
    __shared__ float rs[4], rq[4];
    if ((t & 63) == 0) { rs[t >> 6] = s; rq[t >> 6] = q; }
    __syncthreads();
    if (t == 0) {
        ps[blockIdx.x] = rs[0] + rs[1] + rs[2] + rs[3];
        pq[blockIdx.x] = rq[0] + rq[1] + rq[2] + rq[3];
    }
}

__global__ void tf_stats_fin(const float* __restrict__ ps, const float* __restrict__ pq,
                             const float* __restrict__ gamma, const float* __restrict__ beta,
                             float* __restrict__ AB)
{
    const int ch = threadIdx.x;   // 256 threads, 1 block
    float s = 0.f, q = 0.f;
    #pragma unroll
    for (int sl = 0; sl < 8; ++sl) {
        s += ps[ch * 8 + sl];
        q += pq[ch * 8 + sl];
    }
    const float inv = 1.f / 100352.f;   // nt2*h*w
    const float mean = s * inv;
    const float var = q * inv - mean * mean;
    const float rstd = rsqrtf(var + 1e-5f);
    const float A = gamma[ch] * rstd;
    AB[ch] = A;
    AB[256 + ch] = beta[ch] - mean * A;
}

__global__ void tf_norm(float* __restrict__ out, const float* __restrict__ AB)
{
    const unsigned total4 = 32u * 256u * 784u;  // 6,422,528 float4
    unsigned i = blockIdx.x * 256u + threadIdx.x;
    const unsigned stride = gridDim.x * 256u;
    float4* o4 = (float4*)out;
    for (; i < total4; i += stride) {
        const unsigned ch = (i / 784u) & 255u;
        const float A = AB[ch], B = AB[256 + ch];
        float4 v = o4[i];
        f4v w;
        w.x = v.x * A + B;
        w.y = v.y * A + B;
        w.z = v.z * A + B;
        w.w = v.w * A + B;
        __builtin_nontemporal_store(w, (f4v*)&o4[i]);
    }
}

extern "C" void kernel_launch(void* const* d_in, const int* in_sizes, int n_in,
                              void* d_out, int out_size, void* d_ws, size_t ws_size,
                              hipStream_t stream) {
    const float* x     = (const float*)d_in[0];
    const float* wconv = (const float*)d_in[1];
    const float* bconv = (const float*)d_in[2];
    const float* gamma = (const float*)d_in[3];
    const float* beta  = (const float*)d_in[4];
    float* out = (float*)d_out;

    float* ps = (float*)d_ws;        // [2048]
    float* pq = ps + 2048;           // [2048]
    float* AB = pq + 2048;           // [512]

    tf_fused<<<NBLK, 256, 0, stream>>>(x, wconv, bconv, out);
    tf_stats_part<<<2048, 256, 0, stream>>>(out, ps, pq);
    tf_stats_fin<<<1, 256, 0, stream>>>(ps, pq, gamma, beta, AB);
    tf_norm<<<2048, 256, 0, stream>>>(out, AB);
}